// Round 1
// baseline (115.997 us; speedup 1.0000x reference)
//
#include <hip/hip_runtime.h>

#define BB 8
#define SS 2048
#define HH 128
#define NHH 4
#define DHH 32

typedef _Float16 f16;
typedef f16 f16x4 __attribute__((ext_vector_type(4)));
typedef f16 f16x8 __attribute__((ext_vector_type(8)));
typedef float f32x4 __attribute__((ext_vector_type(4)));

// ---------------- LayerNorm (unbiased std, /(std+eps)) ----------------
// one wave per row of 128; block=256 -> 4 rows/block
template <typename T>
__global__ __launch_bounds__(256) void ln_kernel(const float* __restrict__ x,
                                                 const float* __restrict__ ga,
                                                 const float* __restrict__ gb,
                                                 T* __restrict__ out) {
  int row = blockIdx.x * 4 + (threadIdx.x >> 6);
  int lane = threadIdx.x & 63;
  const float* xr = x + (size_t)row * HH;
  float2 v = *(const float2*)(xr + lane * 2);
  float s = v.x + v.y;
  float ss = v.x * v.x + v.y * v.y;
#pragma unroll
  for (int m = 1; m < 64; m <<= 1) {
    s += __shfl_xor(s, m);
    ss += __shfl_xor(ss, m);
  }
  float mean = s * (1.0f / HH);
  float var = fmaxf((ss - (float)HH * mean * mean) * (1.0f / (HH - 1)), 0.0f);
  float inv = 1.0f / (sqrtf(var) + 1e-6f);
  int c = lane * 2;
  T* o = out + (size_t)row * HH + c;
  o[0] = (T)(ga[c] * (v.x - mean) * inv + gb[c]);
  o[1] = (T)(ga[c + 1] * (v.y - mean) * inv + gb[c + 1]);
}

// ---------------- f16 MFMA flash attention ----------------
// block = 256 thr (4 waves); wave owns 32 queries (2 tiles of 16)
// grid = B * NH * (S/128); keys chunked by 32 (2 key-tiles), K=32=DH per mfma
__global__ __launch_bounds__(256) void attn_kernel(const f16* __restrict__ n1,
                                                   const int* __restrict__ mask,
                                                   const float* __restrict__ scalew,
                                                   float* __restrict__ hatt) {
  const int tid = threadIdx.x;
  const int qc = blockIdx.x & 15;
  const int h = (blockIdx.x >> 4) & (NHH - 1);
  const int b = blockIdx.x >> 6;
  const int wave = tid >> 6;
  const int lane = tid & 63;
  const int lg = lane >> 4;  // k-group 0..3
  const int lm = lane & 15;  // row/col within 16-tile

  // K chunk as [dt(2)][key(32)][16] f16, subtile pad 8 -> stride 520
  __shared__ __align__(16) f16 Klds[2 * 520];
  // V^T chunk as [d(32)][key(32)] f16, row stride 36 (8B-aligned b64 reads)
  __shared__ __align__(16) f16 Vt[32 * 36];
  __shared__ __align__(16) float mb[32];

  const int qbase = qc * 128 + wave * 32;
  const f16* __restrict__ nb = n1 + (size_t)b * SS * HH + h * DHH;

  f16x8 qf[2];
  float sfac[2];
#pragma unroll
  for (int qt = 0; qt < 2; ++qt) {
    int q = qbase + qt * 16 + lm;
    qf[qt] = *(const f16x8*)(nb + (size_t)q * HH + lg * 8);
    sfac[qt] = scalew[h * SS + q] * 0.17677669529663687f;  // 1/sqrt(DH)
  }

  const f32x4 zero = {0.f, 0.f, 0.f, 0.f};
  f32x4 acc[2][2] = {{zero, zero}, {zero, zero}};  // [dtile][qtile]
  float lsum[2] = {0.f, 0.f};

  const int skey = tid >> 3;  // 0..31
  const int spart = tid & 7;  // 0..7 (4 halfs each)
  const int sdt = spart >> 2;
  const int sdd = (spart & 3) * 4;

  for (int c = 0; c < SS / 32; ++c) {
    const int k0 = c * 32;
    __syncthreads();
    {
      f16x4 v = *(const f16x4*)(nb + (size_t)(k0 + skey) * HH + spart * 4);
      *(f16x4*)(&Klds[sdt * 520 + skey * 16 + sdd]) = v;
#pragma unroll
      for (int j = 0; j < 4; ++j) Vt[(spart * 4 + j) * 36 + skey] = v[j];
      if (tid < 32) mb[tid] = (mask[b * SS + k0 + tid] == 0) ? -1e9f : 0.0f;
    }
    __syncthreads();

    // A-frags for S^T = K * Q^T : lane row = key (lm), k-group lg -> d = 8*lg..+7
    f16x8 kf[2];
#pragma unroll
    for (int kt = 0; kt < 2; ++kt)
      kf[kt] = *(const f16x8*)(&Klds[(lg >> 1) * 520 + (kt * 16 + lm) * 16 + (lg & 1) * 8]);

    f32x4 st[2][2];
#pragma unroll
    for (int kt = 0; kt < 2; ++kt)
#pragma unroll
      for (int qt = 0; qt < 2; ++qt)
        st[kt][qt] = __builtin_amdgcn_mfma_f32_16x16x32_f16(kf[kt], qf[qt], zero, 0, 0, 0);

    float4 mv[2];
#pragma unroll
    for (int kt = 0; kt < 2; ++kt) mv[kt] = *(const float4*)(&mb[kt * 16 + lg * 4]);

    // scores -> p = exp(s*sfac + maskbias - 4); lane holds query lm, keys 4*lg+r (+16*kt)
    f16x8 pf[2];
#pragma unroll
    for (int qt = 0; qt < 2; ++qt) {
#pragma unroll
      for (int kt = 0; kt < 2; ++kt) {
        const float* mp = (const float*)&mv[kt];
#pragma unroll
        for (int r = 0; r < 4; ++r) {
          float sfv = st[kt][qt][r] * sfac[qt] + mp[r];
          float pe = __expf(sfv - 4.0f);
          lsum[qt] += pe;
          pf[qt][kt * 4 + r] = (f16)pe;
        }
      }
    }

    // V^T A-frags: reg j holds V[key = 16*(j>>2) + 4*lg + (j&3)][d = vt*16+lm]
    f16x8 vf[2];
#pragma unroll
    for (int vt = 0; vt < 2; ++vt) {
      int d = vt * 16 + lm;
      f16x4 lo = *(const f16x4*)(&Vt[d * 36 + lg * 4]);
      f16x4 hi = *(const f16x4*)(&Vt[d * 36 + 16 + lg * 4]);
      vf[vt] = (f16x8){lo[0], lo[1], lo[2], lo[3], hi[0], hi[1], hi[2], hi[3]};
    }

#pragma unroll
    for (int dt = 0; dt < 2; ++dt)
#pragma unroll
      for (int qt = 0; qt < 2; ++qt)
        acc[dt][qt] = __builtin_amdgcn_mfma_f32_16x16x32_f16(vf[dt], pf[qt], acc[dt][qt], 0, 0, 0);
  }

  // finish softmax denominator: lanes {lm, lm+16, lm+32, lm+48} partition the keys
#pragma unroll
  for (int qt = 0; qt < 2; ++qt) {
    lsum[qt] += __shfl_xor(lsum[qt], 16);
    lsum[qt] += __shfl_xor(lsum[qt], 32);
  }

#pragma unroll
  for (int qt = 0; qt < 2; ++qt) {
    float inv = 1.0f / lsum[qt];
    int q = qbase + qt * 16 + lm;
    float* op = hatt + (size_t)(b * SS + q) * HH + h * DHH;
#pragma unroll
    for (int dt = 0; dt < 2; ++dt)
#pragma unroll
      for (int r = 0; r < 4; ++r) op[dt * 16 + lg * 4 + r] = acc[dt][qt][r] * inv;
  }
}

// ---------------- fp32 GEMM (M-tile 64 x full N=128, K=128) + epilogues ----------------
__global__ __launch_bounds__(256) void gemm_res_kernel(const float* __restrict__ X,
                                                       const float* __restrict__ W,
                                                       const float* __restrict__ bias,
                                                       const float* __restrict__ resid,
                                                       float* __restrict__ out) {
  __shared__ float Wt[128][132];  // W transposed: Wt[k][n] = W[n][k]
  __shared__ float Xs[64][129];
  const int tid = threadIdx.x;
  const int r0 = blockIdx.x * 64;
#pragma unroll 4
  for (int i = tid; i < 128 * 32; i += 256) {
    int n = i >> 5, k4 = (i & 31) * 4;
    float4 w = *(const float4*)(W + (size_t)n * HH + k4);
    Wt[k4][n] = w.x; Wt[k4 + 1][n] = w.y; Wt[k4 + 2][n] = w.z; Wt[k4 + 3][n] = w.w;
  }
#pragma unroll 2
  for (int i = tid; i < 64 * 32; i += 256) {
    int r = i >> 5, k4 = (i & 31) * 4;
    float4 xv = *(const float4*)(X + (size_t)(r0 + r) * HH + k4);
    Xs[r][k4] = xv.x; Xs[r][k4 + 1] = xv.y; Xs[r][k4 + 2] = xv.z; Xs[r][k4 + 3] = xv.w;
  }
  __syncthreads();
  const int cg = tid & 15, rg = tid >> 4;
  float acc[4][8];
#pragma unroll
  for (int i = 0; i < 4; ++i)
#pragma unroll
    for (int j = 0; j < 8; ++j) acc[i][j] = 0.f;
  for (int k = 0; k < 128; ++k) {
    float xr[4];
#pragma unroll
    for (int i = 0; i < 4; ++i) xr[i] = Xs[rg * 4 + i][k];
    float4 w0 = *(const float4*)(&Wt[k][cg * 8]);
    float4 w1 = *(const float4*)(&Wt[k][cg * 8 + 4]);
    float wv[8] = {w0.x, w0.y, w0.z, w0.w, w1.x, w1.y, w1.z, w1.w};
#pragma unroll
    for (int i = 0; i < 4; ++i)
#pragma unroll
      for (int j = 0; j < 8; ++j) acc[i][j] += xr[i] * wv[j];
  }
#pragma unroll
  for (int i = 0; i < 4; ++i) {
    int row = r0 + rg * 4 + i;
#pragma unroll
    for (int j = 0; j < 8; ++j) {
      int cc = cg * 8 + j;
      out[(size_t)row * HH + cc] = resid[(size_t)row * HH + cc] + acc[i][j] + bias[cc];
    }
  }
}

__global__ __launch_bounds__(256) void ffn_kernel(const float* __restrict__ X,
                                                  const float* __restrict__ W,
                                                  const float* __restrict__ bias,
                                                  const float* __restrict__ fscale,
                                                  float* __restrict__ out) {
  __shared__ float Wt[128][132];
  __shared__ float Xs[64][129];
  const int tid = threadIdx.x;
  const int r0 = blockIdx.x * 64;
#pragma unroll 4
  for (int i = tid; i < 128 * 32; i += 256) {
    int n = i >> 5, k4 = (i & 31) * 4;
    float4 w = *(const float4*)(W + (size_t)n * HH + k4);
    Wt[k4][n] = w.x; Wt[k4 + 1][n] = w.y; Wt[k4 + 2][n] = w.z; Wt[k4 + 3][n] = w.w;
  }
#pragma unroll 2
  for (int i = tid; i < 64 * 32; i += 256) {
    int r = i >> 5, k4 = (i & 31) * 4;
    float4 xv = *(const float4*)(X + (size_t)(r0 + r) * HH + k4);
    Xs[r][k4] = xv.x; Xs[r][k4 + 1] = xv.y; Xs[r][k4 + 2] = xv.z; Xs[r][k4 + 3] = xv.w;
  }
  __syncthreads();
  const int cg = tid & 15, rg = tid >> 4;
  float acc[4][8];
#pragma unroll
  for (int i = 0; i < 4; ++i)
#pragma unroll
    for (int j = 0; j < 8; ++j) acc[i][j] = 0.f;
  for (int k = 0; k < 128; ++k) {
    float xr[4];
#pragma unroll
    for (int i = 0; i < 4; ++i) xr[i] = Xs[rg * 4 + i][k];
    float4 w0 = *(const float4*)(&Wt[k][cg * 8]);
    float4 w1 = *(const float4*)(&Wt[k][cg * 8 + 4]);
    float wv[8] = {w0.x, w0.y, w0.z, w0.w, w1.x, w1.y, w1.z, w1.w};
#pragma unroll
    for (int i = 0; i < 4; ++i)
#pragma unroll
      for (int j = 0; j < 8; ++j) acc[i][j] += xr[i] * wv[j];
  }
#pragma unroll
  for (int i = 0; i < 4; ++i) {
    int row = r0 + rg * 4 + i;
    float fs = fscale[row & (SS - 1)];
#pragma unroll
    for (int j = 0; j < 8; ++j) {
      int cc = cg * 8 + j;
      float hf = fs * (acc[i][j] + bias[cc]);
      float u = 0.7978845608028654f * hf * (1.0f + 0.044715f * hf * hf);
      float e = __expf(2.0f * u);
      float t = 1.0f - 2.0f / (e + 1.0f);  // tanh(u)
      float act = 0.5f * hf * (1.0f + t);
      out[(size_t)row * HH + cc] += act;
    }
  }
}

extern "C" void kernel_launch(void* const* d_in, const int* in_sizes, int n_in,
                              void* d_out, int out_size, void* d_ws, size_t ws_size,
                              hipStream_t stream) {
  const float* hidden = (const float*)d_in[0];
  const int* mask = (const int*)d_in[1];
  const float* scalew = (const float*)d_in[2];
  const float* Wl = (const float*)d_in[3];
  const float* bl = (const float*)d_in[4];
  const float* W1 = (const float*)d_in[5];
  const float* b1 = (const float*)d_in[6];
  const float* fscale = (const float*)d_in[7];
  const float* ln1a = (const float*)d_in[8];
  const float* ln1b = (const float*)d_in[9];
  const float* ln2a = (const float*)d_in[10];
  const float* ln2b = (const float*)d_in[11];
  float* out = (float*)d_out;

  f16* n1 = (f16*)d_ws;                                              // 4 MB
  float* hatt = (float*)((char*)d_ws + (size_t)BB * SS * HH * 2);    // 8 MB (reused as n2)

  const int rows = BB * SS;
  ln_kernel<f16><<<rows / 4, 256, 0, stream>>>(hidden, ln1a, ln1b, n1);
  attn_kernel<<<BB * NHH * (SS / 128), 256, 0, stream>>>(n1, mask, scalew, hatt);
  gemm_res_kernel<<<rows / 64, 256, 0, stream>>>(hatt, Wl, bl, hidden, out);
  ln_kernel<float><<<rows / 4, 256, 0, stream>>>(out, ln2a, ln2b, hatt);
  ffn_kernel<<<rows / 64, 256, 0, stream>>>(hatt, W1, b1, fscale, out);
}

// Round 2
// 76.440 us; speedup vs baseline: 1.5175x; 1.5175x over previous
//
#include <hip/hip_runtime.h>

#define BB 8
#define SS 2048
#define HH 128
#define NHH 4
#define DHH 32

typedef _Float16 f16;
typedef f16 f16x4 __attribute__((ext_vector_type(4)));
typedef f16 f16x8 __attribute__((ext_vector_type(8)));
typedef float f32x4 __attribute__((ext_vector_type(4)));

// ---------------- LayerNorm (unbiased std, /(std+eps)) -> f16 ----------------
template <typename T>
__global__ __launch_bounds__(256) void ln_kernel(const float* __restrict__ x,
                                                 const float* __restrict__ ga,
                                                 const float* __restrict__ gb,
                                                 T* __restrict__ out) {
  int row = blockIdx.x * 4 + (threadIdx.x >> 6);
  int lane = threadIdx.x & 63;
  const float* xr = x + (size_t)row * HH;
  float2 v = *(const float2*)(xr + lane * 2);
  float s = v.x + v.y;
  float ss = v.x * v.x + v.y * v.y;
#pragma unroll
  for (int m = 1; m < 64; m <<= 1) {
    s += __shfl_xor(s, m);
    ss += __shfl_xor(ss, m);
  }
  float mean = s * (1.0f / HH);
  float var = fmaxf((ss - (float)HH * mean * mean) * (1.0f / (HH - 1)), 0.0f);
  float inv = 1.0f / (sqrtf(var) + 1e-6f);
  int c = lane * 2;
  T* o = out + (size_t)row * HH + c;
  o[0] = (T)(ga[c] * (v.x - mean) * inv + gb[c]);
  o[1] = (T)(ga[c + 1] * (v.y - mean) * inv + gb[c + 1]);
}

// ---------------- prep: weights->f16, mask->exp2 bias ----------------
__global__ __launch_bounds__(256) void prep_kernel(const float* __restrict__ Wl,
                                                   const float* __restrict__ W1,
                                                   const int* __restrict__ mask,
                                                   f16* __restrict__ Wlf,
                                                   f16* __restrict__ W1f,
                                                   float* __restrict__ mb) {
  int g = blockIdx.x * 256 + threadIdx.x;
  if (g < 4096) {
    float4 w = ((const float4*)Wl)[g];
    f16x4 o = {(f16)w.x, (f16)w.y, (f16)w.z, (f16)w.w};
    ((f16x4*)Wlf)[g] = o;
  } else if (g < 8192) {
    float4 w = ((const float4*)W1)[g - 4096];
    f16x4 o = {(f16)w.x, (f16)w.y, (f16)w.z, (f16)w.w};
    ((f16x4*)W1f)[g - 4096] = o;
  } else {
    int4 m = ((const int4*)mask)[g - 8192];
    float4 o;
    o.x = m.x ? -5.7707801636f : -1.5e9f;  // (-4)*log2e  or  (-1e9)*log2e-ish
    o.y = m.y ? -5.7707801636f : -1.5e9f;
    o.z = m.z ? -5.7707801636f : -1.5e9f;
    o.w = m.w ? -5.7707801636f : -1.5e9f;
    ((float4*)mb)[g - 8192] = o;
  }
}

// ---------------- f16 MFMA flash attention, double-buffered ----------------
// grid = B*NH*(S/64) = 1024; block 256 = 4 waves; wave = 16 queries; chunk = 64 keys
__global__ __launch_bounds__(256, 4) void attn_kernel(const f16* __restrict__ n1,
                                                      const float* __restrict__ mbias,
                                                      const float* __restrict__ scalew,
                                                      f16* __restrict__ hatt) {
  const int tid = threadIdx.x;
  const int qb = blockIdx.x & 31;
  const int h = (blockIdx.x >> 5) & (NHH - 1);
  const int b = blockIdx.x >> 7;
  const int wave = tid >> 6, lane = tid & 63;
  const int lg = lane >> 4, lm = lane & 15;

  __shared__ __align__(16) f16 Kb[2][2][64][16];  // [buf][dhalf][key][8elem*2]
  __shared__ __align__(16) f16 Vt[2][32][68];     // [buf][d][key(+pad)]

  const f16* __restrict__ nb = n1 + (size_t)b * SS * HH + h * DHH;
  const float* __restrict__ mbb = mbias + b * SS;

  const int q = qb * 64 + wave * 16 + lm;
  const f16x8 qf = *(const f16x8*)(nb + (size_t)q * HH + lg * 8);
  const float sc2 = scalew[h * SS + q] * 0.2550680718664f;  // (1/sqrt32)*log2e

  const int kk = tid >> 2, p = tid & 3;  // staging: key kk (0..63), 16B part p
  const f16* sb = nb + (size_t)kk * HH + p * 8;

  const f32x4 zero = {0.f, 0.f, 0.f, 0.f};
  f32x4 acc0 = zero, acc1 = zero;
  float lsum = 0.f;

  // prologue: stage chunk 0, prefetch chunk 1
  f16x8 sreg = *(const f16x8*)(sb);
  *(f16x8*)(&Kb[0][p >> 1][kk][(p & 1) * 8]) = sreg;
#pragma unroll
  for (int j = 0; j < 8; ++j) Vt[0][p * 8 + j][kk] = sreg[j];
  sreg = *(const f16x8*)(sb + (size_t)64 * HH);
  __syncthreads();

  for (int c = 0; c < 32; ++c) {
    const int buf = c & 1;
    f16x8 snext = sreg;
    if (c < 30) snext = *(const f16x8*)(sb + (size_t)(c + 2) * 64 * HH);  // issue early
    const int k0 = c * 64;
#pragma unroll
    for (int ks = 0; ks < 2; ++ks) {
      f16x8 kf0 = *(const f16x8*)(&Kb[buf][lg >> 1][ks * 32 + lm][(lg & 1) * 8]);
      f16x8 kf1 = *(const f16x8*)(&Kb[buf][lg >> 1][ks * 32 + 16 + lm][(lg & 1) * 8]);
      f32x4 st0 = __builtin_amdgcn_mfma_f32_16x16x32_f16(kf0, qf, zero, 0, 0, 0);
      f32x4 st1 = __builtin_amdgcn_mfma_f32_16x16x32_f16(kf1, qf, zero, 0, 0, 0);
      float4 mv0 = *(const float4*)(mbb + k0 + ks * 32 + lg * 4);
      float4 mv1 = *(const float4*)(mbb + k0 + ks * 32 + 16 + lg * 4);
      const float* m0 = &mv0.x;
      const float* m1 = &mv1.x;
      f16x8 pf;
#pragma unroll
      for (int r = 0; r < 4; ++r) {
        float p0 = __builtin_amdgcn_exp2f(st0[r] * sc2 + m0[r]);
        float p1 = __builtin_amdgcn_exp2f(st1[r] * sc2 + m1[r]);
        lsum += p0 + p1;
        pf[r] = (f16)p0;
        pf[4 + r] = (f16)p1;
      }
      const int kb0 = ks * 32 + lg * 4;
      f16x4 v00 = *(const f16x4*)(&Vt[buf][lm][kb0]);
      f16x4 v01 = *(const f16x4*)(&Vt[buf][lm][kb0 + 16]);
      f16x4 v10 = *(const f16x4*)(&Vt[buf][16 + lm][kb0]);
      f16x4 v11 = *(const f16x4*)(&Vt[buf][16 + lm][kb0 + 16]);
      f16x8 vf0 = {v00[0], v00[1], v00[2], v00[3], v01[0], v01[1], v01[2], v01[3]};
      f16x8 vf1 = {v10[0], v10[1], v10[2], v10[3], v11[0], v11[1], v11[2], v11[3]};
      acc0 = __builtin_amdgcn_mfma_f32_16x16x32_f16(vf0, pf, acc0, 0, 0, 0);
      acc1 = __builtin_amdgcn_mfma_f32_16x16x32_f16(vf1, pf, acc1, 0, 0, 0);
    }
    if (c < 31) {  // stage chunk c+1 into other buffer (safe: distinct buffer)
      *(f16x8*)(&Kb[buf ^ 1][p >> 1][kk][(p & 1) * 8]) = sreg;
#pragma unroll
      for (int j = 0; j < 8; ++j) Vt[buf ^ 1][p * 8 + j][kk] = sreg[j];
      sreg = snext;
    }
    __syncthreads();
  }

  lsum += __shfl_xor(lsum, 16);
  lsum += __shfl_xor(lsum, 32);
  float inv = 1.0f / lsum;
  f16* op = hatt + (size_t)(b * SS + q) * HH + h * DHH;
  f16x4 o0 = {(f16)(acc0[0] * inv), (f16)(acc0[1] * inv), (f16)(acc0[2] * inv), (f16)(acc0[3] * inv)};
  f16x4 o1 = {(f16)(acc1[0] * inv), (f16)(acc1[1] * inv), (f16)(acc1[2] * inv), (f16)(acc1[3] * inv)};
  *(f16x4*)(op + lg * 4) = o0;
  *(f16x4*)(op + 16 + lg * 4) = o1;
}

// ---------------- GEMM1: out = resid + X@Wl^T + bl ; fused LN2 -> n2(f16) ----------
// D = W*X^T trick: lane holds one output ROW (col of D). block 128 = 2 waves;
// wave covers 16 rows x 64 cols (4 n-tiles); grid = rows/16 = 1024.
__global__ __launch_bounds__(128) void gemm1_kernel(const f16* __restrict__ X,
                                                    const f16* __restrict__ Wf,
                                                    const float* __restrict__ bl,
                                                    const float* __restrict__ resid,
                                                    const float* __restrict__ ln2a,
                                                    const float* __restrict__ ln2b,
                                                    float* __restrict__ out,
                                                    f16* __restrict__ n2) {
  const int tid = threadIdx.x;
  const int wave = tid >> 6, lane = tid & 63;
  const int lg = lane >> 4, lm = lane & 15;
  const int row = blockIdx.x * 16 + lm;
  const int nc0 = wave * 64;

  f32x4 acc[4] = {};
  const f16* xr = X + (size_t)row * HH;
#pragma unroll
  for (int ks = 0; ks < 4; ++ks) {
    f16x8 bf = *(const f16x8*)(xr + ks * 32 + lg * 8);
#pragma unroll
    for (int nt = 0; nt < 4; ++nt) {
      f16x8 af = *(const f16x8*)(Wf + (size_t)(nc0 + nt * 16 + lm) * HH + ks * 32 + lg * 8);
      acc[nt] = __builtin_amdgcn_mfma_f32_16x16x32_f16(af, bf, acc[nt], 0, 0, 0);
    }
  }
  float sum = 0.f, sq = 0.f;
  f32x4 o[4];
#pragma unroll
  for (int nt = 0; nt < 4; ++nt) {
    int n = nc0 + nt * 16 + lg * 4;
    float4 rv = *(const float4*)(resid + (size_t)row * HH + n);
    float4 bv = *(const float4*)(bl + n);
    f32x4 v = acc[nt];
    v[0] += rv.x + bv.x; v[1] += rv.y + bv.y;
    v[2] += rv.z + bv.z; v[3] += rv.w + bv.w;
    o[nt] = v;
    *(f32x4*)(out + (size_t)row * HH + n) = v;
    sum += v[0] + v[1] + v[2] + v[3];
    sq += v[0] * v[0] + v[1] * v[1] + v[2] * v[2] + v[3] * v[3];
  }
  sum += __shfl_xor(sum, 16); sum += __shfl_xor(sum, 32);
  sq += __shfl_xor(sq, 16);  sq += __shfl_xor(sq, 32);
  __shared__ float red[2][16][2];
  if (lane < 16) { red[wave][lm][0] = sum; red[wave][lm][1] = sq; }
  __syncthreads();
  float ts = red[0][lm][0] + red[1][lm][0];
  float tq = red[0][lm][1] + red[1][lm][1];
  float mean = ts * (1.0f / HH);
  float var = fmaxf((tq - (float)HH * mean * mean) * (1.0f / (HH - 1)), 0.0f);
  float inv = 1.0f / (sqrtf(var) + 1e-6f);
#pragma unroll
  for (int nt = 0; nt < 4; ++nt) {
    int n = nc0 + nt * 16 + lg * 4;
    float4 av = *(const float4*)(ln2a + n);
    float4 b2 = *(const float4*)(ln2b + n);
    f16x4 w;
    w[0] = (f16)(av.x * (o[nt][0] - mean) * inv + b2.x);
    w[1] = (f16)(av.y * (o[nt][1] - mean) * inv + b2.y);
    w[2] = (f16)(av.z * (o[nt][2] - mean) * inv + b2.z);
    w[3] = (f16)(av.w * (o[nt][3] - mean) * inv + b2.w);
    *(f16x4*)(n2 + (size_t)row * HH + n) = w;
  }
}

// ---------------- FFN: out += gelu(fscale*(n2@W1^T + b1)) ----------------
__global__ __launch_bounds__(128) void ffn_kernel(const f16* __restrict__ X,
                                                  const f16* __restrict__ Wf,
                                                  const float* __restrict__ b1,
                                                  const float* __restrict__ fscale,
                                                  float* __restrict__ out) {
  const int tid = threadIdx.x;
  const int wave = tid >> 6, lane = tid & 63;
  const int lg = lane >> 4, lm = lane & 15;
  const int row = blockIdx.x * 16 + lm;
  const int nc0 = wave * 64;

  f32x4 acc[4] = {};
  const f16* xr = X + (size_t)row * HH;
#pragma unroll
  for (int ks = 0; ks < 4; ++ks) {
    f16x8 bf = *(const f16x8*)(xr + ks * 32 + lg * 8);
#pragma unroll
    for (int nt = 0; nt < 4; ++nt) {
      f16x8 af = *(const f16x8*)(Wf + (size_t)(nc0 + nt * 16 + lm) * HH + ks * 32 + lg * 8);
      acc[nt] = __builtin_amdgcn_mfma_f32_16x16x32_f16(af, bf, acc[nt], 0, 0, 0);
    }
  }
  float fs = fscale[row & (SS - 1)];
#pragma unroll
  for (int nt = 0; nt < 4; ++nt) {
    int n = nc0 + nt * 16 + lg * 4;
    float4 bv = *(const float4*)(b1 + n);
    const float* bp = &bv.x;
    f32x4 ov = *(const f32x4*)(out + (size_t)row * HH + n);
#pragma unroll
    for (int e = 0; e < 4; ++e) {
      float hf = fs * (acc[nt][e] + bp[e]);
      float u = 0.7978845608028654f * hf * (1.0f + 0.044715f * hf * hf);
      float ex = __builtin_amdgcn_exp2f(u * 2.8853900817779268f);  // exp(2u)
      float t = 1.0f - 2.0f / (ex + 1.0f);
      ov[e] += 0.5f * hf * (1.0f + t);
    }
    *(f32x4*)(out + (size_t)row * HH + n) = ov;
  }
}

extern "C" void kernel_launch(void* const* d_in, const int* in_sizes, int n_in,
                              void* d_out, int out_size, void* d_ws, size_t ws_size,
                              hipStream_t stream) {
  const float* hidden = (const float*)d_in[0];
  const int* mask = (const int*)d_in[1];
  const float* scalew = (const float*)d_in[2];
  const float* Wl = (const float*)d_in[3];
  const float* bl = (const float*)d_in[4];
  const float* W1 = (const float*)d_in[5];
  const float* b1 = (const float*)d_in[6];
  const float* fscale = (const float*)d_in[7];
  const float* ln1a = (const float*)d_in[8];
  const float* ln1b = (const float*)d_in[9];
  const float* ln2a = (const float*)d_in[10];
  const float* ln2b = (const float*)d_in[11];
  float* out = (float*)d_out;

  const size_t NE = (size_t)BB * SS * HH;  // 2M elements
  f16* n1 = (f16*)d_ws;
  f16* hattf = n1 + NE;
  f16* n2 = hattf + NE;
  f16* Wlf = n2 + NE;
  f16* W1f = Wlf + HH * HH;
  float* mb = (float*)(W1f + HH * HH);

  const int rows = BB * SS;
  prep_kernel<<<48, 256, 0, stream>>>(Wl, W1, mask, Wlf, W1f, mb);
  ln_kernel<f16><<<rows / 4, 256, 0, stream>>>(hidden, ln1a, ln1b, n1);
  attn_kernel<<<BB * NHH * (SS / 64), 256, 0, stream>>>(n1, mb, scalew, hattf);
  gemm1_kernel<<<rows / 16, 128, 0, stream>>>(hattf, Wlf, bl, hidden, ln2a, ln2b, out, n2);
  ffn_kernel<<<rows / 16, 128, 0, stream>>>(n2, W1f, b1, fscale, out);
}

// Round 3
// 74.223 us; speedup vs baseline: 1.5628x; 1.0299x over previous
//
#include <hip/hip_runtime.h>

#define BB 8
#define SS 2048
#define HH 128
#define NHH 4
#define DHH 32

typedef _Float16 f16;
typedef f16 f16x4 __attribute__((ext_vector_type(4)));
typedef f16 f16x8 __attribute__((ext_vector_type(8)));
typedef float f32x4 __attribute__((ext_vector_type(4)));

// ---------------- LayerNorm (unbiased std, /(std+eps)) -> f16 ----------------
template <typename T>
__global__ __launch_bounds__(256) void ln_kernel(const float* __restrict__ x,
                                                 const float* __restrict__ ga,
                                                 const float* __restrict__ gb,
                                                 T* __restrict__ out) {
  int row = blockIdx.x * 4 + (threadIdx.x >> 6);
  int lane = threadIdx.x & 63;
  const float* xr = x + (size_t)row * HH;
  float2 v = *(const float2*)(xr + lane * 2);
  float s = v.x + v.y;
  float ss = v.x * v.x + v.y * v.y;
#pragma unroll
  for (int m = 1; m < 64; m <<= 1) {
    s += __shfl_xor(s, m);
    ss += __shfl_xor(ss, m);
  }
  float mean = s * (1.0f / HH);
  float var = fmaxf((ss - (float)HH * mean * mean) * (1.0f / (HH - 1)), 0.0f);
  float inv = 1.0f / (sqrtf(var) + 1e-6f);
  int c = lane * 2;
  T* o = out + (size_t)row * HH + c;
  o[0] = (T)(ga[c] * (v.x - mean) * inv + gb[c]);
  o[1] = (T)(ga[c + 1] * (v.y - mean) * inv + gb[c + 1]);
}

// ---------------- prep: weights->f16, mask->exp2 bias ----------------
__global__ __launch_bounds__(256) void prep_kernel(const float* __restrict__ Wl,
                                                   const float* __restrict__ W1,
                                                   const int* __restrict__ mask,
                                                   f16* __restrict__ Wlf,
                                                   f16* __restrict__ W1f,
                                                   float* __restrict__ mb) {
  int g = blockIdx.x * 256 + threadIdx.x;
  if (g < 4096) {
    float4 w = ((const float4*)Wl)[g];
    f16x4 o = {(f16)w.x, (f16)w.y, (f16)w.z, (f16)w.w};
    ((f16x4*)Wlf)[g] = o;
  } else if (g < 8192) {
    float4 w = ((const float4*)W1)[g - 4096];
    f16x4 o = {(f16)w.x, (f16)w.y, (f16)w.z, (f16)w.w};
    ((f16x4*)W1f)[g - 4096] = o;
  } else {
    int4 m = ((const int4*)mask)[g - 8192];
    float4 o;
    o.x = m.x ? -5.7707801636f : -1.5e9f;  // (-4)*log2e  or  -inf-ish
    o.y = m.y ? -5.7707801636f : -1.5e9f;
    o.z = m.z ? -5.7707801636f : -1.5e9f;
    o.w = m.w ? -5.7707801636f : -1.5e9f;
    ((float4*)mb)[g - 8192] = o;
  }
}

// hardware transpose read: lane l, elem j <- lds[(l&15) + j*16 + (l>>4)*64] (f16 units)
__device__ __forceinline__ f16x4 tr_read(const f16* p) {
  f16x4 d;
  asm volatile("ds_read_b64_tr_b16 %0, %1"
               : "=v"(d)
               : "v"((__attribute__((address_space(3))) const f16*)p)
               : "memory");
  return d;
}

// ---------------- f16 MFMA flash attention, wave-private, barrier-free ------
// grid = B*NH*(S/64) = 1024; block 256 = 4 waves; wave = 16 queries, streams all keys
__global__ __launch_bounds__(256, 4) void attn_kernel(const f16* __restrict__ n1,
                                                      const float* __restrict__ mbias,
                                                      const float* __restrict__ scalew,
                                                      f16* __restrict__ hatt) {
  const int tid = threadIdx.x;
  const int qb = blockIdx.x & 31;
  const int h = (blockIdx.x >> 5) & (NHH - 1);
  const int b = blockIdx.x >> 7;
  const int wave = tid >> 6, lane = tid & 63;
  const int lg = lane >> 4, lm = lane & 15;

  __shared__ __align__(16) f16 Kall[4][2][64][16];  // per-wave [dhalf][key][16d]
  f16(*Kb)[64][16] = Kall[wave];

  const f16* __restrict__ nb = n1 + (size_t)b * SS * HH + h * DHH;
  const float* __restrict__ mbb = mbias + b * SS;

  const int q = qb * 64 + wave * 16 + lm;
  const f16x8 qf = *(const f16x8*)(nb + (size_t)q * HH + lg * 8);
  const float sc2 = scalew[h * SS + q] * 0.2550680718664f;  // (1/sqrt32)*log2e

  // staging: lane handles keys {skey, skey+16, skey+32, skey+48}, 16B part sp
  const int skey = lane >> 2, sp = lane & 3;
  const f16* sbase = nb + (size_t)skey * HH + sp * 8;
  f16* wbase = &Kb[sp >> 1][skey][(sp & 1) * 8];

  const f32x4 zero = {0.f, 0.f, 0.f, 0.f};
  f32x4 acc0 = zero, acc1 = zero;
  float lsum = 0.f;

  // prologue: stage chunk 0
  f16x8 sreg[4];
#pragma unroll
  for (int i = 0; i < 4; ++i) sreg[i] = *(const f16x8*)(sbase + (size_t)i * 16 * HH);
#pragma unroll
  for (int i = 0; i < 4; ++i) *(f16x8*)(wbase + i * 256) = sreg[i];

  for (int c = 0; c < 32; ++c) {
    const int k0 = c * 64;
    // issue next chunk's global loads early (latency hides under compute)
    f16x8 nreg[4];
    if (c < 31) {
#pragma unroll
      for (int i = 0; i < 4; ++i)
        nreg[i] = *(const f16x8*)(sbase + (size_t)((c + 1) * 64 + i * 16) * HH);
    }
    float4 mv[4];
#pragma unroll
    for (int t = 0; t < 4; ++t) mv[t] = *(const float4*)(mbb + k0 + t * 16 + lg * 4);

    // QK^T: S^T tiles, lane holds q=lm, keys t*16 + 4*lg + r
    f32x4 st[4];
#pragma unroll
    for (int t = 0; t < 4; ++t) {
      f16x8 kf = *(const f16x8*)(&Kb[lg >> 1][t * 16 + lm][(lg & 1) * 8]);
      st[t] = __builtin_amdgcn_mfma_f32_16x16x32_f16(kf, qf, zero, 0, 0, 0);
    }

    f16x8 pf[2];
#pragma unroll
    for (int t = 0; t < 4; ++t) {
      const float* mp = &mv[t].x;
#pragma unroll
      for (int r = 0; r < 4; ++r) {
        float pe = __builtin_amdgcn_exp2f(st[t][r] * sc2 + mp[r]);
        lsum += pe;
        pf[t >> 1][(t & 1) * 4 + r] = (f16)pe;
      }
    }

    // PV: V^T fragments via HW transpose reads (keys = ktile + 4*lg + j, d = dh*16 + lm)
    f16x4 a00 = tr_read(&Kb[0][0][0] + lane * 4);
    f16x4 a01 = tr_read(&Kb[0][16][0] + lane * 4);
    f16x4 a10 = tr_read(&Kb[1][0][0] + lane * 4);
    f16x4 a11 = tr_read(&Kb[1][16][0] + lane * 4);
    f16x4 c00 = tr_read(&Kb[0][32][0] + lane * 4);
    f16x4 c01 = tr_read(&Kb[0][48][0] + lane * 4);
    f16x4 c10 = tr_read(&Kb[1][32][0] + lane * 4);
    f16x4 c11 = tr_read(&Kb[1][48][0] + lane * 4);
    asm volatile("s_waitcnt lgkmcnt(0)" ::: "memory");
    __builtin_amdgcn_sched_barrier(0);

    f16x8 vf;
    vf = (f16x8){a00[0], a00[1], a00[2], a00[3], a01[0], a01[1], a01[2], a01[3]};
    acc0 = __builtin_amdgcn_mfma_f32_16x16x32_f16(vf, pf[0], acc0, 0, 0, 0);
    vf = (f16x8){a10[0], a10[1], a10[2], a10[3], a11[0], a11[1], a11[2], a11[3]};
    acc1 = __builtin_amdgcn_mfma_f32_16x16x32_f16(vf, pf[0], acc1, 0, 0, 0);
    vf = (f16x8){c00[0], c00[1], c00[2], c00[3], c01[0], c01[1], c01[2], c01[3]};
    acc0 = __builtin_amdgcn_mfma_f32_16x16x32_f16(vf, pf[1], acc0, 0, 0, 0);
    vf = (f16x8){c10[0], c10[1], c10[2], c10[3], c11[0], c11[1], c11[2], c11[3]};
    acc1 = __builtin_amdgcn_mfma_f32_16x16x32_f16(vf, pf[1], acc1, 0, 0, 0);

    // stage chunk c+1 (per-wave DS is in-order: writes can't pass the tr-reads above)
    if (c < 31) {
#pragma unroll
      for (int i = 0; i < 4; ++i) *(f16x8*)(wbase + i * 256) = nreg[i];
    }
  }

  lsum += __shfl_xor(lsum, 16);
  lsum += __shfl_xor(lsum, 32);
  float inv = 1.0f / lsum;
  f16* op = hatt + (size_t)(b * SS + q) * HH + h * DHH;
  f16x4 o0 = {(f16)(acc0[0] * inv), (f16)(acc0[1] * inv), (f16)(acc0[2] * inv), (f16)(acc0[3] * inv)};
  f16x4 o1 = {(f16)(acc1[0] * inv), (f16)(acc1[1] * inv), (f16)(acc1[2] * inv), (f16)(acc1[3] * inv)};
  *(f16x4*)(op + lg * 4) = o0;
  *(f16x4*)(op + 16 + lg * 4) = o1;
}

// ---------------- GEMM1: out = resid + X@Wl^T + bl ; fused LN2 -> n2(f16) ----------
__global__ __launch_bounds__(128) void gemm1_kernel(const f16* __restrict__ X,
                                                    const f16* __restrict__ Wf,
                                                    const float* __restrict__ bl,
                                                    const float* __restrict__ resid,
                                                    const float* __restrict__ ln2a,
                                                    const float* __restrict__ ln2b,
                                                    float* __restrict__ out,
                                                    f16* __restrict__ n2) {
  const int tid = threadIdx.x;
  const int wave = tid >> 6, lane = tid & 63;
  const int lg = lane >> 4, lm = lane & 15;
  const int row = blockIdx.x * 16 + lm;
  const int nc0 = wave * 64;

  f32x4 acc[4] = {};
  const f16* xr = X + (size_t)row * HH;
#pragma unroll
  for (int ks = 0; ks < 4; ++ks) {
    f16x8 bf = *(const f16x8*)(xr + ks * 32 + lg * 8);
#pragma unroll
    for (int nt = 0; nt < 4; ++nt) {
      f16x8 af = *(const f16x8*)(Wf + (size_t)(nc0 + nt * 16 + lm) * HH + ks * 32 + lg * 8);
      acc[nt] = __builtin_amdgcn_mfma_f32_16x16x32_f16(af, bf, acc[nt], 0, 0, 0);
    }
  }
  float sum = 0.f, sq = 0.f;
  f32x4 o[4];
#pragma unroll
  for (int nt = 0; nt < 4; ++nt) {
    int n = nc0 + nt * 16 + lg * 4;
    float4 rv = *(const float4*)(resid + (size_t)row * HH + n);
    float4 bv = *(const float4*)(bl + n);
    f32x4 v = acc[nt];
    v[0] += rv.x + bv.x; v[1] += rv.y + bv.y;
    v[2] += rv.z + bv.z; v[3] += rv.w + bv.w;
    o[nt] = v;
    *(f32x4*)(out + (size_t)row * HH + n) = v;
    sum += v[0] + v[1] + v[2] + v[3];
    sq += v[0] * v[0] + v[1] * v[1] + v[2] * v[2] + v[3] * v[3];
  }
  sum += __shfl_xor(sum, 16); sum += __shfl_xor(sum, 32);
  sq += __shfl_xor(sq, 16);  sq += __shfl_xor(sq, 32);
  __shared__ float red[2][16][2];
  if (lane < 16) { red[wave][lm][0] = sum; red[wave][lm][1] = sq; }
  __syncthreads();
  float ts = red[0][lm][0] + red[1][lm][0];
  float tq = red[0][lm][1] + red[1][lm][1];
  float mean = ts * (1.0f / HH);
  float var = fmaxf((tq - (float)HH * mean * mean) * (1.0f / (HH - 1)), 0.0f);
  float inv = 1.0f / (sqrtf(var) + 1e-6f);
#pragma unroll
  for (int nt = 0; nt < 4; ++nt) {
    int n = nc0 + nt * 16 + lg * 4;
    float4 av = *(const float4*)(ln2a + n);
    float4 b2 = *(const float4*)(ln2b + n);
    f16x4 w;
    w[0] = (f16)(av.x * (o[nt][0] - mean) * inv + b2.x);
    w[1] = (f16)(av.y * (o[nt][1] - mean) * inv + b2.y);
    w[2] = (f16)(av.z * (o[nt][2] - mean) * inv + b2.z);
    w[3] = (f16)(av.w * (o[nt][3] - mean) * inv + b2.w);
    *(f16x4*)(n2 + (size_t)row * HH + n) = w;
  }
}

// ---------------- FFN: out += gelu(fscale*(n2@W1^T + b1)) ----------------
__global__ __launch_bounds__(128) void ffn_kernel(const f16* __restrict__ X,
                                                  const f16* __restrict__ Wf,
                                                  const float* __restrict__ b1,
                                                  const float* __restrict__ fscale,
                                                  float* __restrict__ out) {
  const int tid = threadIdx.x;
  const int wave = tid >> 6, lane = tid & 63;
  const int lg = lane >> 4, lm = lane & 15;
  const int row = blockIdx.x * 16 + lm;
  const int nc0 = wave * 64;

  f32x4 acc[4] = {};
  const f16* xr = X + (size_t)row * HH;
#pragma unroll
  for (int ks = 0; ks < 4; ++ks) {
    f16x8 bf = *(const f16x8*)(xr + ks * 32 + lg * 8);
#pragma unroll
    for (int nt = 0; nt < 4; ++nt) {
      f16x8 af = *(const f16x8*)(Wf + (size_t)(nc0 + nt * 16 + lm) * HH + ks * 32 + lg * 8);
      acc[nt] = __builtin_amdgcn_mfma_f32_16x16x32_f16(af, bf, acc[nt], 0, 0, 0);
    }
  }
  float fs = fscale[row & (SS - 1)];
#pragma unroll
  for (int nt = 0; nt < 4; ++nt) {
    int n = nc0 + nt * 16 + lg * 4;
    float4 bv = *(const float4*)(b1 + n);
    const float* bp = &bv.x;
    f32x4 ov = *(const f32x4*)(out + (size_t)row * HH + n);
#pragma unroll
    for (int e = 0; e < 4; ++e) {
      float hf = fs * (acc[nt][e] + bp[e]);
      float u = 0.7978845608028654f * hf * (1.0f + 0.044715f * hf * hf);
      float ex = __builtin_amdgcn_exp2f(u * 2.8853900817779268f);  // exp(2u)
      float t = 1.0f - 2.0f / (ex + 1.0f);
      ov[e] += 0.5f * hf * (1.0f + t);
    }
    *(f32x4*)(out + (size_t)row * HH + n) = ov;
  }
}

extern "C" void kernel_launch(void* const* d_in, const int* in_sizes, int n_in,
                              void* d_out, int out_size, void* d_ws, size_t ws_size,
                              hipStream_t stream) {
  const float* hidden = (const float*)d_in[0];
  const int* mask = (const int*)d_in[1];
  const float* scalew = (const float*)d_in[2];
  const float* Wl = (const float*)d_in[3];
  const float* bl = (const float*)d_in[4];
  const float* W1 = (const float*)d_in[5];
  const float* b1 = (const float*)d_in[6];
  const float* fscale = (const float*)d_in[7];
  const float* ln1a = (const float*)d_in[8];
  const float* ln1b = (const float*)d_in[9];
  const float* ln2a = (const float*)d_in[10];
  const float* ln2b = (const float*)d_in[11];
  float* out = (float*)d_out;

  const size_t NE = (size_t)BB * SS * HH;  // 2M elements
  f16* n1 = (f16*)d_ws;
  f16* hattf = n1 + NE;
  f16* n2 = hattf + NE;
  f16* Wlf = n2 + NE;
  f16* W1f = Wlf + HH * HH;
  float* mb = (float*)(W1f + HH * HH);

  const int rows = BB * SS;
  prep_kernel<<<48, 256, 0, stream>>>(Wl, W1, mask, Wlf, W1f, mb);
  ln_kernel<f16><<<rows / 4, 256, 0, stream>>>(hidden, ln1a, ln1b, n1);
  attn_kernel<<<BB * NHH * (SS / 64), 256, 0, stream>>>(n1, mb, scalew, hattf);
  gemm1_kernel<<<rows / 16, 128, 0, stream>>>(hattf, Wlf, bl, hidden, ln2a, ln2b, out, n2);
  ffn_kernel<<<rows / 16, 128, 0, stream>>>(n2, W1f, b1, fscale, out);
}